// Round 14
// baseline (166.165 us; speedup 1.0000x reference)
//
#include <hip/hip_runtime.h>

#define E_EDGES 8192
#define N_COMP  20000
#define N_IND   500
#define NKEYS   512

typedef short bf16x8 __attribute__((ext_vector_type(8)));
typedef float f32x4  __attribute__((ext_vector_type(4)));

static __device__ __forceinline__ unsigned short f2bf(float v) {
    unsigned u = __builtin_bit_cast(unsigned, v);
    u = (u + 0x7FFFu + ((u >> 16) & 1u)) >> 16;
    return (unsigned short)u;
}

static __device__ __forceinline__ void cvt8(const float* __restrict__ s,
                                            unsigned short* __restrict__ d) {
    float4 a = *(const float4*)s;
    float4 b = *(const float4*)(s + 4);
    bf16x8 o;
    o[0] = (short)f2bf(a.x); o[1] = (short)f2bf(a.y);
    o[2] = (short)f2bf(a.z); o[3] = (short)f2bf(a.w);
    o[4] = (short)f2bf(b.x); o[5] = (short)f2bf(b.y);
    o[6] = (short)f2bf(b.z); o[7] = (short)f2bf(b.w);
    *(bf16x8*)d = o;
}

static __device__ __forceinline__ bf16x8 cvt8r(const float* __restrict__ s) {
    float4 a = *(const float4*)s;
    float4 b = *(const float4*)(s + 4);
    bf16x8 v;
    v[0] = (short)f2bf(a.x); v[1] = (short)f2bf(a.y);
    v[2] = (short)f2bf(a.z); v[3] = (short)f2bf(a.w);
    v[4] = (short)f2bf(b.x); v[5] = (short)f2bf(b.y);
    v[6] = (short)f2bf(b.z); v[7] = (short)f2bf(b.w);
    return v;
}

#define SWZ(r)   (((r) & 7) << 4)
#define SWZ4(r)  ((((r) >> 1) & 3) << 4)

static __device__ __forceinline__ void stage_f32(const float* src, char* base,
                                                 int sr, int sc) {
    *(bf16x8*)(base + ((sr * 64 + sc * 2) ^ SWZ(sr))) = cvt8r(src);
}

// ---------------------------------------------------------------------------
// prep: block-range-dispatched preprocessing (unchanged, known-good).
// ---------------------------------------------------------------------------
__global__ __launch_bounds__(256) void prep(
    const int* __restrict__ src, const int* __restrict__ tgt,
    const float* __restrict__ Wc, const float* __restrict__ Wi,
    const float* __restrict__ w_out, const float* __restrict__ w_in,
    const float* __restrict__ bc, const float* __restrict__ bi,
    const float* __restrict__ b_in,
    float* __restrict__ csrc, float* __restrict__ ctgt,
    unsigned short* __restrict__ Wc_bf, unsigned short* __restrict__ wout_bf,
    unsigned short* __restrict__ WcT_bf, unsigned short* __restrict__ Wi_bf,
    unsigned short* __restrict__ wkv_bf, float* __restrict__ beff)
{
    const int bid = blockIdx.x, tid = threadIdx.x;
    if (bid < 32) {
        int e = bid * 256 + tid;
        atomicAdd(&csrc[src[e]], 1.0f);
        atomicAdd(&ctgt[tgt[e]], 1.0f);
    } else if (bid < 64) {
        long i = ((long)(bid - 32) * 256 + tid) * 8;
        cvt8(Wc + i, Wc_bf + i);
    } else if (bid < 96) {
        long i = ((long)(bid - 64) * 256 + tid) * 8;
        cvt8(w_out + i, wout_bf + i);
    } else if (bid < 128) {
        long o = ((long)(bid - 96) * 256 + tid) * 8;
        int c = (int)(o >> 8), d0 = (int)(o & 255);
        bf16x8 v;
#pragma unroll
        for (int j = 0; j < 8; j++) v[j] = (short)f2bf(Wc[(long)(d0 + j) * 256 + c]);
        *(bf16x8*)(WcT_bf + o) = v;
    } else if (bid < 144) {
        long i = ((long)(bid - 128) * 256 + tid) * 8;
        cvt8(Wi + i, Wi_bf + i);
    } else if (bid < 208) {
        long i = ((long)(bid - 144) * 256 + tid) * 8;
        cvt8(w_in + 65536 + i, wkv_bf + i);
    } else {
        int gi = (bid - 208) * 256 + tid;      // [0, 3072)
        int e = gi >> 2, q = gi & 3;
        const float* base = (e < 256) ? bc : bi;
        const float* wr = w_in + (long)e * 256 + q * 64;
        const float* br = base + q * 64;
        float s = 0.f;
#pragma unroll
        for (int j = 0; j < 64; j += 4) {
            float4 w4 = *(const float4*)(wr + j);
            float4 b4 = *(const float4*)(br + j);
            s += w4.x * b4.x + w4.y * b4.y + w4.z * b4.z + w4.w * b4.w;
        }
        s += __shfl_xor(s, 1);
        s += __shfl_xor(s, 2);
        if (q == 0) beff[e] = s + b_in[e];
    }
}

// ---------------------------------------------------------------------------
// fusedW (LDS-staged; list/compaction removed — only cntT in finalize).
// grid = 22: [0,4) Wcq; [4,20) K/VT; [20,22) cntT transpose.
// ---------------------------------------------------------------------------
__global__ __launch_bounds__(256) void fusedW(
    const float* __restrict__ w_in, const unsigned short* __restrict__ WcT_bf,
    const float* __restrict__ industry_x, const unsigned short* __restrict__ Wi_bf,
    const unsigned short* __restrict__ wkv_bf, const float* __restrict__ beff,
    const float* __restrict__ ctgt,
    unsigned short* __restrict__ Wcq_bf, unsigned short* __restrict__ Kbuf,
    unsigned short* __restrict__ VTg, float* __restrict__ cntT)
{
    const int bid = blockIdx.x;
    if (bid >= 20) {
        int i = (bid - 20) * 256 + threadIdx.x;
        if (i < NKEYS) cntT[(i & 15) * 32 + (i >> 4)] = ctgt[i];
        return;
    }

    __shared__ char lds[48 * 1024];
    const int t = threadIdx.x, wv = t >> 6, lane = t & 63;
    const int g = lane >> 4, ln = lane & 15;
    const int sr = t >> 2, sc = (t & 3) * 8;

    if (bid < 4) {
        char* ab = lds;
        char* wb = lds + 4 * 1024;
        const int bm = bid * 64;
        f32x4 acc[16];
#pragma unroll
        for (int i = 0; i < 16; i++) acc[i] = (f32x4){0.f, 0.f, 0.f, 0.f};
        const float* aptr = w_in + (long)(bm + sr) * 256 + sc;
        for (int kc = 0; kc < 256; kc += 32) {
            __syncthreads();
            stage_f32(aptr + kc, ab, sr, sc);
#pragma unroll
            for (int p = 0; p < 4; p++) {
                int r = p * 64 + sr;
                *(bf16x8*)(wb + ((r * 64 + sc * 2) ^ SWZ(r))) =
                    *(const bf16x8*)(WcT_bf + (long)r * 256 + kc + sc);
            }
            __syncthreads();
            int ar = wv * 16 + ln;
            bf16x8 af = *(bf16x8*)(ab + ((ar * 64 + g * 16) ^ SWZ(ar)));
#pragma unroll
            for (int nj = 0; nj < 16; nj++) {
                int wr = nj * 16 + ln;
                bf16x8 bf = *(bf16x8*)(wb + ((wr * 64 + g * 16) ^ SWZ(wr)));
                acc[nj] = __builtin_amdgcn_mfma_f32_16x16x32_bf16(af, bf, acc[nj], 0, 0, 0);
            }
        }
#pragma unroll
        for (int nj = 0; nj < 16; nj++)
#pragma unroll
            for (int r = 0; r < 4; r++)
                Wcq_bf[(long)(bm + wv * 16 + g * 4 + r) * 256 + nj * 16 + ln] =
                    f2bf(acc[nj][r]);
        return;
    }

    const int rg = (bid - 4) >> 1, colh = (bid - 4) & 1;
    char* ab  = lds;
    char* wb1 = lds + 4 * 1024;
    char* ihb = lds + 16 * 1024;
    char* wb2 = lds;

    {
        f32x4 a1[16];
#pragma unroll
        for (int i = 0; i < 16; i++) a1[i] = (f32x4){0.f, 0.f, 0.f, 0.f};
        int arow = rg * 64 + sr; if (arow > N_IND - 1) arow = N_IND - 1;
        const float* aptr = industry_x + (long)arow * 128 + sc;
        for (int kc = 0; kc < 128; kc += 32) {
            __syncthreads();
            stage_f32(aptr + kc, ab, sr, sc);
#pragma unroll
            for (int p = 0; p < 4; p++) {
                int r = p * 64 + sr;
                *(bf16x8*)(wb1 + ((r * 64 + sc * 2) ^ SWZ(r))) =
                    *(const bf16x8*)(Wi_bf + (long)r * 128 + kc + sc);
            }
            __syncthreads();
            int ar = wv * 16 + ln;
            bf16x8 af = *(bf16x8*)(ab + ((ar * 64 + g * 16) ^ SWZ(ar)));
#pragma unroll
            for (int nj = 0; nj < 16; nj++) {
                int wr = nj * 16 + ln;
                bf16x8 bf = *(bf16x8*)(wb1 + ((wr * 64 + g * 16) ^ SWZ(wr)));
                a1[nj] = __builtin_amdgcn_mfma_f32_16x16x32_bf16(af, bf, a1[nj], 0, 0, 0);
            }
        }
        __syncthreads();
#pragma unroll
        for (int nj = 0; nj < 16; nj++)
#pragma unroll
            for (int r = 0; r < 4; r++) {
                int row = wv * 16 + g * 4 + r, col = nj * 16 + ln;
                *(unsigned short*)(ihb + ((row * 512 + col * 2) ^ SWZ(row))) =
                    f2bf(a1[nj][r]);
            }
    }
    __syncthreads();

    if (colh == 0) {
        f32x4 a2[16];
#pragma unroll
        for (int i = 0; i < 16; i++) a2[i] = (f32x4){0.f, 0.f, 0.f, 0.f};
        for (int kc = 0; kc < 256; kc += 32) {
            __syncthreads();
#pragma unroll
            for (int p = 0; p < 4; p++) {
                int r = p * 64 + sr;
                *(bf16x8*)(wb2 + ((r * 64 + sc * 2) ^ SWZ(r))) =
                    *(const bf16x8*)(wkv_bf + (long)r * 256 + kc + sc);
            }
            __syncthreads();
            int row = wv * 16 + ln;
            bf16x8 af = *(bf16x8*)(ihb + ((row * 512 + (kc + g * 8) * 2) ^ SWZ(row)));
#pragma unroll
            for (int nj = 0; nj < 16; nj++) {
                int wr = nj * 16 + ln;
                bf16x8 bf = *(bf16x8*)(wb2 + ((wr * 64 + g * 16) ^ SWZ(wr)));
                a2[nj] = __builtin_amdgcn_mfma_f32_16x16x32_bf16(af, bf, a2[nj], 0, 0, 0);
            }
        }
#pragma unroll
        for (int nj = 0; nj < 16; nj++)
#pragma unroll
            for (int r = 0; r < 4; r++) {
                int R = rg * 64 + wv * 16 + g * 4 + r, n = nj * 16 + ln;
                Kbuf[(long)R * 256 + n] = f2bf(a2[nj][r] + beff[256 + n]);
            }
    } else {
        const unsigned short* wp = wkv_bf + 65536;
        f32x4 a2[16];
#pragma unroll
        for (int i = 0; i < 16; i++) a2[i] = (f32x4){0.f, 0.f, 0.f, 0.f};
        for (int kc = 0; kc < 256; kc += 32) {
            __syncthreads();
#pragma unroll
            for (int p = 0; p < 4; p++) {
                int r = p * 64 + sr;
                *(bf16x8*)(wb2 + ((r * 64 + sc * 2) ^ SWZ(r))) =
                    *(const bf16x8*)(wp + (long)r * 256 + kc + sc);
            }
            __syncthreads();
#pragma unroll
            for (int mi = 0; mi < 4; mi++) {
                int arow = wv * 64 + mi * 16 + ln;
                bf16x8 af = *(bf16x8*)(wb2 + ((arow * 64 + g * 16) ^ SWZ(arow)));
#pragma unroll
                for (int t4 = 0; t4 < 4; t4++) {
                    int brow = t4 * 16 + ln;
                    bf16x8 bfr = *(bf16x8*)(ihb + ((brow * 512 + (kc + g * 8) * 2) ^ SWZ(brow)));
                    a2[mi * 4 + t4] = __builtin_amdgcn_mfma_f32_16x16x32_bf16(af, bfr, a2[mi * 4 + t4], 0, 0, 0);
                }
            }
        }
#pragma unroll
        for (int mi = 0; mi < 4; mi++)
#pragma unroll
            for (int t4 = 0; t4 < 4; t4++)
#pragma unroll
                for (int r = 0; r < 4; r++) {
                    int nrow = wv * 64 + mi * 16 + g * 4 + r;
                    VTg[(long)nrow * 512 + rg * 64 + t4 * 16 + ln] =
                        f2bf(a2[mi * 4 + t4][r] + beff[512 + nrow]);
                }
    }
}

// ---------------------------------------------------------------------------
// mega: everything per 16 companies in ONE kernel. grid = 1250, 4 waves,
// wave = head. Phases: stage x -> {company GEMM + Q proj} (shared A-frag) ->
// attention (all rows; factor=0 kills it for edge-less companies) -> ctx LDS
// -> out-proj -> cross-wave LayerNorm -> out. No list, no pooled buffer.
// ---------------------------------------------------------------------------
__global__ __launch_bounds__(256, 2) void mega(
    const float* __restrict__ company_x,
    const unsigned short* __restrict__ Wc_bf,
    const float* __restrict__ bc,
    const unsigned short* __restrict__ Wcq,
    const float* __restrict__ beff,
    const unsigned short* __restrict__ Kbuf,
    const unsigned short* __restrict__ VTg,
    const float* __restrict__ cntT,
    const unsigned short* __restrict__ wout,
    const float* __restrict__ b_out,
    const float* __restrict__ csrc,
    const float* __restrict__ gamma, const float* __restrict__ beta,
    float* __restrict__ out)
{
    const int bm = blockIdx.x * 16;           // 1250 * 16 = 20000 exactly
    __shared__ char lds[33280];
    const int t = threadIdx.x, h = t >> 6, lane = t & 63;
    const int g = lane >> 4, ln = lane & 15;
    char* xbase   = lds;                      // [16][256] bf16 (8 KB)
    char* ctxbase = lds + 8192;               // [16][256] bf16 (8 KB)
    char* pbase   = lds + 16384 + h * 4096;   // wave-private scratch (q + P)
    float* psum   = (float*)(lds + 32768);    // [16][4]
    float* psq    = psum + 64;                // [16][4]

    // ---- 1. stage x ----
    {
        int row = t >> 4, c0 = (t & 15) * 16;
        const float* src = company_x + (long)(bm + row) * 256 + c0;
        *(bf16x8*)(xbase + ((row * 512 + c0 * 2) ^ SWZ(row))) = cvt8r(src);
        *(bf16x8*)(xbase + ((row * 512 + c0 * 2 + 16) ^ SWZ(row))) = cvt8r(src + 8);
    }
    __syncthreads();

    // ---- 2. company GEMM (cols [64h,64h+64)) + Q proj, shared A-frag ----
    f32x4 ch[4], qa[4];
#pragma unroll
    for (int i = 0; i < 4; i++) {
        ch[i] = (f32x4){0.f, 0.f, 0.f, 0.f};
        qa[i] = (f32x4){0.f, 0.f, 0.f, 0.f};
    }
#pragma unroll
    for (int kc = 0; kc < 256; kc += 32) {
        bf16x8 af = *(bf16x8*)(xbase + ((ln * 512 + (kc + g * 8) * 2) ^ SWZ(ln)));
#pragma unroll
        for (int nj = 0; nj < 4; nj++) {
            long wrow = (long)(h * 64 + nj * 16 + ln) * 256 + kc + g * 8;
            bf16x8 b1 = *(const bf16x8*)(Wc_bf + wrow);
            bf16x8 b2 = *(const bf16x8*)(Wcq + wrow);
            ch[nj] = __builtin_amdgcn_mfma_f32_16x16x32_bf16(af, b1, ch[nj], 0, 0, 0);
            qa[nj] = __builtin_amdgcn_mfma_f32_16x16x32_bf16(af, b2, qa[nj], 0, 0, 0);
        }
    }

    // ---- 3. q relayout (wave-private LDS) -> qf regs ----
    bf16x8 qf0, qf1;
    {
#pragma unroll
        for (int nj = 0; nj < 4; nj++)
#pragma unroll
            for (int r = 0; r < 4; r++) {
                int row = g * 4 + r, col = nj * 16 + ln;
                *(unsigned short*)(pbase + ((row * 128 + col * 2) ^ SWZ(row))) =
                    f2bf((qa[nj][r] + beff[h * 64 + col]) * 0.125f);
            }
        qf0 = *(bf16x8*)(pbase + ((ln * 128 + g * 16) ^ SWZ(ln)));
        qf1 = *(bf16x8*)(pbase + ((ln * 128 + 64 + g * 16) ^ SWZ(ln)));
    }

    // ---- 4. flash attention, 2 tiles x 256 keys ----
    f32x4 acc[4];
#pragma unroll
    for (int i = 0; i < 4; i++) acc[i] = (f32x4){0.f, 0.f, 0.f, 0.f};
    float mreg[4] = {-1e30f, -1e30f, -1e30f, -1e30f};
    float lreg[4] = {0.f, 0.f, 0.f, 0.f};

#pragma unroll
    for (int tile = 0; tile < 2; tile++) {
        float cnt[16];
        {
            const float* cp = cntT + ln * 32 + tile * 16;
#pragma unroll
            for (int j4 = 0; j4 < 4; j4++) {
                float4 c4 = *(const float4*)(cp + j4 * 4);
                cnt[j4 * 4 + 0] = c4.x; cnt[j4 * 4 + 1] = c4.y;
                cnt[j4 * 4 + 2] = c4.z; cnt[j4 * 4 + 3] = c4.w;
            }
        }

        // QK^T: grouped loads (16 dests in flight per half)
        f32x4 S[8][2];
#pragma unroll
        for (int half = 0; half < 2; half++) {
            bf16x8 k0r[4][2], k1r[4][2];
#pragma unroll
            for (int c4 = 0; c4 < 4; c4++)
#pragma unroll
                for (int sub = 0; sub < 2; sub++) {
                    const unsigned short* kr = Kbuf +
                        (long)(tile * 256 + (half * 4 + c4) * 32 + sub * 16 + ln) * 256 + h * 64 + g * 8;
                    k0r[c4][sub] = *(const bf16x8*)(kr);
                    k1r[c4][sub] = *(const bf16x8*)(kr + 32);
                }
#pragma unroll
            for (int c4 = 0; c4 < 4; c4++)
#pragma unroll
                for (int sub = 0; sub < 2; sub++) {
                    f32x4 s = (f32x4){0.f, 0.f, 0.f, 0.f};
                    s = __builtin_amdgcn_mfma_f32_16x16x32_bf16(qf0, k0r[c4][sub], s, 0, 0, 0);
                    s = __builtin_amdgcn_mfma_f32_16x16x32_bf16(qf1, k1r[c4][sub], s, 0, 0, 0);
                    S[half * 4 + c4][sub] = s;
                }
        }

        // prefetch VT chunk 0 before softmax
        bf16x8 vr[2][4];
#pragma unroll
        for (int t4 = 0; t4 < 4; t4++)
            vr[0][t4] = *(const bf16x8*)(
                VTg + (long)(h * 64 + t4 * 16 + ln) * 512 + tile * 256 + g * 8);

        float tm[4] = {-1e30f, -1e30f, -1e30f, -1e30f};
#pragma unroll
        for (int c = 0; c < 8; c++)
#pragma unroll
            for (int sub = 0; sub < 2; sub++)
#pragma unroll
                for (int r = 0; r < 4; r++) tm[r] = fmaxf(tm[r], S[c][sub][r]);
#pragma unroll
        for (int st = 1; st < 16; st <<= 1)
#pragma unroll
            for (int r = 0; r < 4; r++) tm[r] = fmaxf(tm[r], __shfl_xor(tm[r], st));

        float corr[4];
#pragma unroll
        for (int r = 0; r < 4; r++) {
            float mn = fmaxf(mreg[r], tm[r]);
            corr[r] = __expf(mreg[r] - mn);
            mreg[r] = mn;
        }

        float ps[4] = {0.f, 0.f, 0.f, 0.f};
#pragma unroll
        for (int c = 0; c < 8; c++)
#pragma unroll
            for (int sub = 0; sub < 2; sub++) {
                float cv = cnt[c * 2 + sub];
#pragma unroll
                for (int r = 0; r < 4; r++) {
                    float p = cv * __expf(S[c][sub][r] - mreg[r]);
                    S[c][sub][r] = p;
                    ps[r] += p;
                }
            }
#pragma unroll
        for (int st = 1; st < 16; st <<= 1)
#pragma unroll
            for (int r = 0; r < 4; r++) ps[r] += __shfl_xor(ps[r], st);
#pragma unroll
        for (int r = 0; r < 4; r++) lreg[r] = lreg[r] * corr[r] + ps[r];
#pragma unroll
        for (int i = 0; i < 4; i++)
#pragma unroll
            for (int r = 0; r < 4; r++) acc[i][r] *= corr[r];

        // PV: 8 chunks, 1-ahead VT prefetch, 2-slot P buffer
#pragma unroll
        for (int c = 0; c < 8; c++) {
            if (c < 7) {
#pragma unroll
                for (int t4 = 0; t4 < 4; t4++)
                    vr[(c + 1) & 1][t4] = *(const bf16x8*)(
                        VTg + (long)(h * 64 + t4 * 16 + ln) * 512 +
                        tile * 256 + (c + 1) * 32 + g * 8);
            }
            char* pb = pbase + (c & 1) * 1024;
#pragma unroll
            for (int sub = 0; sub < 2; sub++)
#pragma unroll
                for (int r = 0; r < 4; r++) {
                    int row = g * 4 + r;
                    *(unsigned short*)(pb + ((row * 64 + (sub * 16 + ln) * 2) ^ SWZ4(row))) =
                        f2bf(S[c][sub][r]);
                }
            bf16x8 pa = *(bf16x8*)(pb + ((ln * 64 + g * 16) ^ SWZ4(ln)));
#pragma unroll
            for (int t4 = 0; t4 < 4; t4++)
                acc[t4] = __builtin_amdgcn_mfma_f32_16x16x32_bf16(
                    pa, vr[c & 1][t4], acc[t4], 0, 0, 0);
        }
    }

    // ---- 5. ctx -> LDS (cols [64h,64h+64) of all 16 rows) ----
#pragma unroll
    for (int t4 = 0; t4 < 4; t4++)
#pragma unroll
        for (int r = 0; r < 4; r++) {
            int row = g * 4 + r, col = h * 64 + t4 * 16 + ln;
            *(unsigned short*)(ctxbase + ((row * 512 + col * 2) ^ SWZ(row))) =
                f2bf(acc[t4][r] / lreg[r]);
        }
    __syncthreads();

    // ---- 6. out-proj cols [64h,64h+64) from full ctx ----
    f32x4 oa[4];
#pragma unroll
    for (int i = 0; i < 4; i++) oa[i] = (f32x4){0.f, 0.f, 0.f, 0.f};
#pragma unroll
    for (int kc = 0; kc < 256; kc += 32) {
        bf16x8 af = *(bf16x8*)(ctxbase + ((ln * 512 + (kc + g * 8) * 2) ^ SWZ(ln)));
#pragma unroll
        for (int nj = 0; nj < 4; nj++) {
            bf16x8 bf = *(const bf16x8*)(wout + (long)(h * 64 + nj * 16 + ln) * 256 + kc + g * 8);
            oa[nj] = __builtin_amdgcn_mfma_f32_16x16x32_bf16(af, bf, oa[nj], 0, 0, 0);
        }
    }

    // ---- 7. LayerNorm: per-wave partials, cross-wave LDS reduce ----
    float v[4][4];
#pragma unroll
    for (int r = 0; r < 4; r++) {
        int R = bm + g * 4 + r;
        float cntv = csrc[R];
        float factor = (cntv > 0.f) ? cntv / (cntv + 1e-6f) : 0.f;
        float s = 0.f, sq = 0.f;
#pragma unroll
        for (int nj = 0; nj < 4; nj++) {
            int n = h * 64 + nj * 16 + ln;
            float x = ch[nj][r] + bc[n] + factor * (oa[nj][r] + b_out[n]);
            v[r][nj] = x;
            s += x;
            sq += x * x;
        }
#pragma unroll
        for (int st = 1; st < 16; st <<= 1) {
            s  += __shfl_xor(s,  st);
            sq += __shfl_xor(sq, st);
        }
        if (ln == 0) {
            psum[(g * 4 + r) * 4 + h] = s;
            psq[(g * 4 + r) * 4 + h]  = sq;
        }
    }
    __syncthreads();

#pragma unroll
    for (int r = 0; r < 4; r++) {
        int row = g * 4 + r;
        int R = bm + row;
        float tot  = psum[row * 4 + 0] + psum[row * 4 + 1] +
                     psum[row * 4 + 2] + psum[row * 4 + 3];
        float totq = psq[row * 4 + 0] + psq[row * 4 + 1] +
                     psq[row * 4 + 2] + psq[row * 4 + 3];
        float mean = tot * (1.0f / 256.0f);
        float var  = totq * (1.0f / 256.0f) - mean * mean;
        float rstd = rsqrtf(var + 1e-5f);
#pragma unroll
        for (int nj = 0; nj < 4; nj++) {
            int n = h * 64 + nj * 16 + ln;
            out[(long)R * 256 + n] = (v[r][nj] - mean) * rstd * gamma[n] + beta[n];
        }
    }
}

// ---------------------------------------------------------------------------
extern "C" void kernel_launch(void* const* d_in, const int* in_sizes, int n_in,
                              void* d_out, int out_size, void* d_ws, size_t ws_size,
                              hipStream_t stream)
{
    const float* company_x  = (const float*)d_in[0];
    const float* industry_x = (const float*)d_in[1];
    const int*   edge       = (const int*)d_in[2];
    const float* Wc         = (const float*)d_in[3];
    const float* bc         = (const float*)d_in[4];
    const float* Wi         = (const float*)d_in[5];
    const float* bi         = (const float*)d_in[6];
    const float* w_in       = (const float*)d_in[7];
    const float* b_in       = (const float*)d_in[8];
    const float* w_out      = (const float*)d_in[9];
    const float* b_out      = (const float*)d_in[10];
    const float* gamma      = (const float*)d_in[11];
    const float* beta       = (const float*)d_in[12];
    float* out = (float*)d_out;

    const int* src = edge;
    const int* tgt = edge + E_EDGES;

    // workspace carve (float units)
    float* wf = (float*)d_ws;
    size_t o = 0;
    unsigned short* Wc_bf   = (unsigned short*)(wf + o); o += 32768;  // 256x256
    unsigned short* wout_bf = (unsigned short*)(wf + o); o += 32768;
    unsigned short* WcT_bf  = (unsigned short*)(wf + o); o += 32768;
    unsigned short* Wi_bf   = (unsigned short*)(wf + o); o += 16384;  // 256x128
    unsigned short* wkv_bf  = (unsigned short*)(wf + o); o += 65536;  // 512x256
    unsigned short* Wcq_bf  = (unsigned short*)(wf + o); o += 32768;
    unsigned short* Kbuf    = (unsigned short*)(wf + o); o += 65536;  // 512x256
    unsigned short* VTg     = (unsigned short*)(wf + o); o += 65536;  // 256x512
    float* beff             = wf + o; o += 768;
    float* cntT             = wf + o; o += NKEYS;
    // contiguous zeroed region: csrc | ctgt
    float* csrc             = wf + o; o += N_COMP;
    float* ctgt             = wf + o; o += NKEYS;

    hipMemsetAsync(csrc, 0, (N_COMP + NKEYS) * sizeof(float), stream);

    prep<<<dim3(220), dim3(256), 0, stream>>>(
        src, tgt, Wc, Wi, w_out, w_in, bc, bi, b_in,
        csrc, ctgt, Wc_bf, wout_bf, WcT_bf, Wi_bf, wkv_bf, beff);

    fusedW<<<dim3(22), dim3(256), 0, stream>>>(
        w_in, WcT_bf, industry_x, Wi_bf, wkv_bf, beff, ctgt,
        Wcq_bf, Kbuf, VTg, cntT);

    mega<<<dim3(N_COMP / 16), dim3(256), 0, stream>>>(
        company_x, Wc_bf, bc, Wcq_bf, beff, Kbuf, VTg, cntT,
        wout_bf, b_out, csrc, gamma, beta, out);
}

// Round 15
// 112.496 us; speedup vs baseline: 1.4771x; 1.4771x over previous
//
#include <hip/hip_runtime.h>

#define E_EDGES 8192
#define N_COMP  20000
#define N_IND   500
#define NKEYS   512

typedef short bf16x8 __attribute__((ext_vector_type(8)));
typedef float f32x4  __attribute__((ext_vector_type(4)));

static __device__ __forceinline__ unsigned short f2bf(float v) {
    unsigned u = __builtin_bit_cast(unsigned, v);
    u = (u + 0x7FFFu + ((u >> 16) & 1u)) >> 16;
    return (unsigned short)u;
}

static __device__ __forceinline__ void cvt8(const float* __restrict__ s,
                                            unsigned short* __restrict__ d) {
    float4 a = *(const float4*)s;
    float4 b = *(const float4*)(s + 4);
    bf16x8 o;
    o[0] = (short)f2bf(a.x); o[1] = (short)f2bf(a.y);
    o[2] = (short)f2bf(a.z); o[3] = (short)f2bf(a.w);
    o[4] = (short)f2bf(b.x); o[5] = (short)f2bf(b.y);
    o[6] = (short)f2bf(b.z); o[7] = (short)f2bf(b.w);
    *(bf16x8*)d = o;
}

static __device__ __forceinline__ bf16x8 cvt8r(const float* __restrict__ s) {
    float4 a = *(const float4*)s;
    float4 b = *(const float4*)(s + 4);
    bf16x8 v;
    v[0] = (short)f2bf(a.x); v[1] = (short)f2bf(a.y);
    v[2] = (short)f2bf(a.z); v[3] = (short)f2bf(a.w);
    v[4] = (short)f2bf(b.x); v[5] = (short)f2bf(b.y);
    v[6] = (short)f2bf(b.z); v[7] = (short)f2bf(b.w);
    return v;
}

#define SWZ(r)   (((r) & 7) << 4)
#define SWZ4(r)  ((((r) >> 1) & 3) << 4)

static __device__ __forceinline__ void stage_f32(const float* src, char* base,
                                                 int sr, int sc) {
    *(bf16x8*)(base + ((sr * 64 + sc * 2) ^ SWZ(sr))) = cvt8r(src);
}

// ---------------------------------------------------------------------------
// prep (unchanged, known-good).
// ---------------------------------------------------------------------------
__global__ __launch_bounds__(256) void prep(
    const int* __restrict__ src, const int* __restrict__ tgt,
    const float* __restrict__ Wc, const float* __restrict__ Wi,
    const float* __restrict__ w_out, const float* __restrict__ w_in,
    const float* __restrict__ bc, const float* __restrict__ bi,
    const float* __restrict__ b_in,
    float* __restrict__ csrc, float* __restrict__ ctgt,
    unsigned short* __restrict__ Wc_bf, unsigned short* __restrict__ wout_bf,
    unsigned short* __restrict__ WcT_bf, unsigned short* __restrict__ Wi_bf,
    unsigned short* __restrict__ wkv_bf, float* __restrict__ beff)
{
    const int bid = blockIdx.x, tid = threadIdx.x;
    if (bid < 32) {
        int e = bid * 256 + tid;
        atomicAdd(&csrc[src[e]], 1.0f);
        atomicAdd(&ctgt[tgt[e]], 1.0f);
    } else if (bid < 64) {
        long i = ((long)(bid - 32) * 256 + tid) * 8;
        cvt8(Wc + i, Wc_bf + i);
    } else if (bid < 96) {
        long i = ((long)(bid - 64) * 256 + tid) * 8;
        cvt8(w_out + i, wout_bf + i);
    } else if (bid < 128) {
        long o = ((long)(bid - 96) * 256 + tid) * 8;
        int c = (int)(o >> 8), d0 = (int)(o & 255);
        bf16x8 v;
#pragma unroll
        for (int j = 0; j < 8; j++) v[j] = (short)f2bf(Wc[(long)(d0 + j) * 256 + c]);
        *(bf16x8*)(WcT_bf + o) = v;
    } else if (bid < 144) {
        long i = ((long)(bid - 128) * 256 + tid) * 8;
        cvt8(Wi + i, Wi_bf + i);
    } else if (bid < 208) {
        long i = ((long)(bid - 144) * 256 + tid) * 8;
        cvt8(w_in + 65536 + i, wkv_bf + i);
    } else {
        int gi = (bid - 208) * 256 + tid;      // [0, 3072)
        int e = gi >> 2, q = gi & 3;
        const float* base = (e < 256) ? bc : bi;
        const float* wr = w_in + (long)e * 256 + q * 64;
        const float* br = base + q * 64;
        float s = 0.f;
#pragma unroll
        for (int j = 0; j < 64; j += 4) {
            float4 w4 = *(const float4*)(wr + j);
            float4 b4 = *(const float4*)(br + j);
            s += w4.x * b4.x + w4.y * b4.y + w4.z * b4.z + w4.w * b4.w;
        }
        s += __shfl_xor(s, 1);
        s += __shfl_xor(s, 2);
        if (q == 0) beff[e] = s + b_in[e];
    }
}

// ---------------------------------------------------------------------------
// fusedW (LDS-staged; with list compaction — unchanged from round 13).
// ---------------------------------------------------------------------------
__global__ __launch_bounds__(256) void fusedW(
    const float* __restrict__ w_in, const unsigned short* __restrict__ WcT_bf,
    const float* __restrict__ industry_x, const unsigned short* __restrict__ Wi_bf,
    const unsigned short* __restrict__ wkv_bf, const float* __restrict__ beff,
    const float* __restrict__ ctgt, const float* __restrict__ csrc,
    unsigned short* __restrict__ Wcq_bf, unsigned short* __restrict__ Kbuf,
    unsigned short* __restrict__ VTg,
    float* __restrict__ cntT, int* __restrict__ list, int* __restrict__ nlist)
{
    const int bid = blockIdx.x;
    if (bid >= 20) {
        int i = (bid - 20) * 256 + threadIdx.x;
        if (i < NKEYS) cntT[(i & 15) * 32 + (i >> 4)] = ctgt[i];
        if (i < N_COMP && csrc[i] > 0.f) {
            int k = atomicAdd(nlist, 1);
            list[k] = i;
        }
        return;
    }

    __shared__ char lds[48 * 1024];
    const int t = threadIdx.x, wv = t >> 6, lane = t & 63;
    const int g = lane >> 4, ln = lane & 15;
    const int sr = t >> 2, sc = (t & 3) * 8;

    if (bid < 4) {
        char* ab = lds;
        char* wb = lds + 4 * 1024;
        const int bm = bid * 64;
        f32x4 acc[16];
#pragma unroll
        for (int i = 0; i < 16; i++) acc[i] = (f32x4){0.f, 0.f, 0.f, 0.f};
        const float* aptr = w_in + (long)(bm + sr) * 256 + sc;
        for (int kc = 0; kc < 256; kc += 32) {
            __syncthreads();
            stage_f32(aptr + kc, ab, sr, sc);
#pragma unroll
            for (int p = 0; p < 4; p++) {
                int r = p * 64 + sr;
                *(bf16x8*)(wb + ((r * 64 + sc * 2) ^ SWZ(r))) =
                    *(const bf16x8*)(WcT_bf + (long)r * 256 + kc + sc);
            }
            __syncthreads();
            int ar = wv * 16 + ln;
            bf16x8 af = *(bf16x8*)(ab + ((ar * 64 + g * 16) ^ SWZ(ar)));
#pragma unroll
            for (int nj = 0; nj < 16; nj++) {
                int wr = nj * 16 + ln;
                bf16x8 bf = *(bf16x8*)(wb + ((wr * 64 + g * 16) ^ SWZ(wr)));
                acc[nj] = __builtin_amdgcn_mfma_f32_16x16x32_bf16(af, bf, acc[nj], 0, 0, 0);
            }
        }
#pragma unroll
        for (int nj = 0; nj < 16; nj++)
#pragma unroll
            for (int r = 0; r < 4; r++)
                Wcq_bf[(long)(bm + wv * 16 + g * 4 + r) * 256 + nj * 16 + ln] =
                    f2bf(acc[nj][r]);
        return;
    }

    const int rg = (bid - 4) >> 1, colh = (bid - 4) & 1;
    char* ab  = lds;
    char* wb1 = lds + 4 * 1024;
    char* ihb = lds + 16 * 1024;
    char* wb2 = lds;

    {
        f32x4 a1[16];
#pragma unroll
        for (int i = 0; i < 16; i++) a1[i] = (f32x4){0.f, 0.f, 0.f, 0.f};
        int arow = rg * 64 + sr; if (arow > N_IND - 1) arow = N_IND - 1;
        const float* aptr = industry_x + (long)arow * 128 + sc;
        for (int kc = 0; kc < 128; kc += 32) {
            __syncthreads();
            stage_f32(aptr + kc, ab, sr, sc);
#pragma unroll
            for (int p = 0; p < 4; p++) {
                int r = p * 64 + sr;
                *(bf16x8*)(wb1 + ((r * 64 + sc * 2) ^ SWZ(r))) =
                    *(const bf16x8*)(Wi_bf + (long)r * 128 + kc + sc);
            }
            __syncthreads();
            int ar = wv * 16 + ln;
            bf16x8 af = *(bf16x8*)(ab + ((ar * 64 + g * 16) ^ SWZ(ar)));
#pragma unroll
            for (int nj = 0; nj < 16; nj++) {
                int wr = nj * 16 + ln;
                bf16x8 bf = *(bf16x8*)(wb1 + ((wr * 64 + g * 16) ^ SWZ(wr)));
                a1[nj] = __builtin_amdgcn_mfma_f32_16x16x32_bf16(af, bf, a1[nj], 0, 0, 0);
            }
        }
        __syncthreads();
#pragma unroll
        for (int nj = 0; nj < 16; nj++)
#pragma unroll
            for (int r = 0; r < 4; r++) {
                int row = wv * 16 + g * 4 + r, col = nj * 16 + ln;
                *(unsigned short*)(ihb + ((row * 512 + col * 2) ^ SWZ(row))) =
                    f2bf(a1[nj][r]);
            }
    }
    __syncthreads();

    if (colh == 0) {
        f32x4 a2[16];
#pragma unroll
        for (int i = 0; i < 16; i++) a2[i] = (f32x4){0.f, 0.f, 0.f, 0.f};
        for (int kc = 0; kc < 256; kc += 32) {
            __syncthreads();
#pragma unroll
            for (int p = 0; p < 4; p++) {
                int r = p * 64 + sr;
                *(bf16x8*)(wb2 + ((r * 64 + sc * 2) ^ SWZ(r))) =
                    *(const bf16x8*)(wkv_bf + (long)r * 256 + kc + sc);
            }
            __syncthreads();
            int row = wv * 16 + ln;
            bf16x8 af = *(bf16x8*)(ihb + ((row * 512 + (kc + g * 8) * 2) ^ SWZ(row)));
#pragma unroll
            for (int nj = 0; nj < 16; nj++) {
                int wr = nj * 16 + ln;
                bf16x8 bf = *(bf16x8*)(wb2 + ((wr * 64 + g * 16) ^ SWZ(wr)));
                a2[nj] = __builtin_amdgcn_mfma_f32_16x16x32_bf16(af, bf, a2[nj], 0, 0, 0);
            }
        }
#pragma unroll
        for (int nj = 0; nj < 16; nj++)
#pragma unroll
            for (int r = 0; r < 4; r++) {
                int R = rg * 64 + wv * 16 + g * 4 + r, n = nj * 16 + ln;
                Kbuf[(long)R * 256 + n] = f2bf(a2[nj][r] + beff[256 + n]);
            }
    } else {
        const unsigned short* wp = wkv_bf + 65536;
        f32x4 a2[16];
#pragma unroll
        for (int i = 0; i < 16; i++) a2[i] = (f32x4){0.f, 0.f, 0.f, 0.f};
        for (int kc = 0; kc < 256; kc += 32) {
            __syncthreads();
#pragma unroll
            for (int p = 0; p < 4; p++) {
                int r = p * 64 + sr;
                *(bf16x8*)(wb2 + ((r * 64 + sc * 2) ^ SWZ(r))) =
                    *(const bf16x8*)(wp + (long)r * 256 + kc + sc);
            }
            __syncthreads();
#pragma unroll
            for (int mi = 0; mi < 4; mi++) {
                int arow = wv * 64 + mi * 16 + ln;
                bf16x8 af = *(bf16x8*)(wb2 + ((arow * 64 + g * 16) ^ SWZ(arow)));
#pragma unroll
                for (int t4 = 0; t4 < 4; t4++) {
                    int brow = t4 * 16 + ln;
                    bf16x8 bfr = *(bf16x8*)(ihb + ((brow * 512 + (kc + g * 8) * 2) ^ SWZ(brow)));
                    a2[mi * 4 + t4] = __builtin_amdgcn_mfma_f32_16x16x32_bf16(af, bfr, a2[mi * 4 + t4], 0, 0, 0);
                }
            }
        }
#pragma unroll
        for (int mi = 0; mi < 4; mi++)
#pragma unroll
            for (int t4 = 0; t4 < 4; t4++)
#pragma unroll
                for (int r = 0; r < 4; r++) {
                    int nrow = wv * 64 + mi * 16 + g * 4 + r;
                    VTg[(long)nrow * 512 + rg * 64 + t4 * 16 + ln] =
                        f2bf(a2[mi * 4 + t4][r] + beff[512 + nrow]);
                }
    }
}

// ---------------------------------------------------------------------------
// attn_gemm: heterogeneous block-range dispatch.
//  blocks [0,1024): attention PARTIAL, (qt = bid>>1, ks = bid&1): 16 listed
//    rows x 4 heads x 256 keys -> (accP, mP, lP). Half the serial chain of
//    the round-13 kernel; exact partials for log-sum-exp merge.
//  blocks [1024,1337): company GEMM (LDS-staged) -> ch fp32. These
//    throughput-bound blocks backfill CU bubbles left by the latency-bound
//    attention blocks.
// ---------------------------------------------------------------------------
__global__ __launch_bounds__(256, 2) void attn_gemm(
    const float* __restrict__ company_x,
    const unsigned short* __restrict__ Wcq,
    const float* __restrict__ beff,
    const unsigned short* __restrict__ Kbuf,
    const unsigned short* __restrict__ VTg,
    const float* __restrict__ cntT,
    const int* __restrict__ list, const int* __restrict__ nlist,
    const unsigned short* __restrict__ Wc_bf, const float* __restrict__ bc,
    float* __restrict__ accP, float* __restrict__ mP, float* __restrict__ lP,
    float* __restrict__ ch)
{
    __shared__ char lds[32768];
    const int bid = blockIdx.x;
    const int t = threadIdx.x, lane = t & 63;
    const int g = lane >> 4, ln = lane & 15;

    if (bid < 1024) {
        // ================= attention partial =================
        const int M = *nlist;
        const int qt = bid >> 1, ks = bid & 1;
        const int bm = qt * 16;
        if (bm >= M) return;
        const int h = t >> 6;
        char* qb    = lds + h * 2048;
        char* xbase = lds + 8192;
        char* pbase = lds + 16384 + h * 4096;

        // stage x
        {
            int row = t >> 4, c0 = (t & 15) * 16;
            int mr = bm + row; if (mr > M - 1) mr = M - 1;
            const float* src = company_x + (long)list[mr] * 256 + c0;
            *(bf16x8*)(xbase + ((row * 512 + c0 * 2) ^ SWZ(row))) = cvt8r(src);
            *(bf16x8*)(xbase + ((row * 512 + c0 * 2 + 16) ^ SWZ(row))) = cvt8r(src + 8);
        }
        __syncthreads();

        // Q
        bf16x8 qf0, qf1;
        {
            f32x4 qa[4];
#pragma unroll
            for (int i = 0; i < 4; i++) qa[i] = (f32x4){0.f, 0.f, 0.f, 0.f};
#pragma unroll
            for (int kc = 0; kc < 256; kc += 32) {
                bf16x8 af = *(bf16x8*)(xbase + ((ln * 512 + (kc + g * 8) * 2) ^ SWZ(ln)));
#pragma unroll
                for (int nj = 0; nj < 4; nj++) {
                    bf16x8 bf = *(const bf16x8*)(Wcq + (long)(h * 64 + nj * 16 + ln) * 256 + kc + g * 8);
                    qa[nj] = __builtin_amdgcn_mfma_f32_16x16x32_bf16(af, bf, qa[nj], 0, 0, 0);
                }
            }
#pragma unroll
            for (int nj = 0; nj < 4; nj++)
#pragma unroll
                for (int r = 0; r < 4; r++) {
                    int row = g * 4 + r, col = nj * 16 + ln;
                    *(unsigned short*)(qb + ((row * 128 + col * 2) ^ SWZ(row))) =
                        f2bf((qa[nj][r] + beff[h * 64 + col]) * 0.125f);
                }
            qf0 = *(bf16x8*)(qb + ((ln * 128 + g * 16) ^ SWZ(ln)));
            qf1 = *(bf16x8*)(qb + ((ln * 128 + 64 + g * 16) ^ SWZ(ln)));
        }

        // counts for this half
        float cnt[16];
        {
            const float* cp = cntT + ln * 32 + ks * 16;
#pragma unroll
            for (int j4 = 0; j4 < 4; j4++) {
                float4 c4 = *(const float4*)(cp + j4 * 4);
                cnt[j4 * 4 + 0] = c4.x; cnt[j4 * 4 + 1] = c4.y;
                cnt[j4 * 4 + 2] = c4.z; cnt[j4 * 4 + 3] = c4.w;
            }
        }

        // QK^T over 256 keys (grouped loads)
        f32x4 S[8][2];
#pragma unroll
        for (int half = 0; half < 2; half++) {
            bf16x8 k0r[4][2], k1r[4][2];
#pragma unroll
            for (int c4 = 0; c4 < 4; c4++)
#pragma unroll
                for (int sub = 0; sub < 2; sub++) {
                    const unsigned short* kr = Kbuf +
                        (long)(ks * 256 + (half * 4 + c4) * 32 + sub * 16 + ln) * 256 + h * 64 + g * 8;
                    k0r[c4][sub] = *(const bf16x8*)(kr);
                    k1r[c4][sub] = *(const bf16x8*)(kr + 32);
                }
#pragma unroll
            for (int c4 = 0; c4 < 4; c4++)
#pragma unroll
                for (int sub = 0; sub < 2; sub++) {
                    f32x4 s = (f32x4){0.f, 0.f, 0.f, 0.f};
                    s = __builtin_amdgcn_mfma_f32_16x16x32_bf16(qf0, k0r[c4][sub], s, 0, 0, 0);
                    s = __builtin_amdgcn_mfma_f32_16x16x32_bf16(qf1, k1r[c4][sub], s, 0, 0, 0);
                    S[half * 4 + c4][sub] = s;
                }
        }

        // prefetch VT chunk 0 before softmax
        bf16x8 vr[2][4];
#pragma unroll
        for (int t4 = 0; t4 < 4; t4++)
            vr[0][t4] = *(const bf16x8*)(
                VTg + (long)(h * 64 + t4 * 16 + ln) * 512 + ks * 256 + g * 8);

        // single-pass softmax over this half
        float tm[4] = {-1e30f, -1e30f, -1e30f, -1e30f};
#pragma unroll
        for (int c = 0; c < 8; c++)
#pragma unroll
            for (int sub = 0; sub < 2; sub++)
#pragma unroll
                for (int r = 0; r < 4; r++) tm[r] = fmaxf(tm[r], S[c][sub][r]);
#pragma unroll
        for (int st = 1; st < 16; st <<= 1)
#pragma unroll
            for (int r = 0; r < 4; r++) tm[r] = fmaxf(tm[r], __shfl_xor(tm[r], st));

        float ps[4] = {0.f, 0.f, 0.f, 0.f};
#pragma unroll
        for (int c = 0; c < 8; c++)
#pragma unroll
            for (int sub = 0; sub < 2; sub++) {
                float cv = cnt[c * 2 + sub];
#pragma unroll
                for (int r = 0; r < 4; r++) {
                    float p = cv * __expf(S[c][sub][r] - tm[r]);
                    S[c][sub][r] = p;
                    ps[r] += p;
                }
            }
#pragma unroll
        for (int st = 1; st < 16; st <<= 1)
#pragma unroll
            for (int r = 0; r < 4; r++) ps[r] += __shfl_xor(ps[r], st);

        // PV (1-ahead VT prefetch, 2-slot P buffer)
        f32x4 acc[4];
#pragma unroll
        for (int i = 0; i < 4; i++) acc[i] = (f32x4){0.f, 0.f, 0.f, 0.f};
#pragma unroll
        for (int c = 0; c < 8; c++) {
            if (c < 7) {
#pragma unroll
                for (int t4 = 0; t4 < 4; t4++)
                    vr[(c + 1) & 1][t4] = *(const bf16x8*)(
                        VTg + (long)(h * 64 + t4 * 16 + ln) * 512 +
                        ks * 256 + (c + 1) * 32 + g * 8);
            }
            char* pb = pbase + (c & 1) * 1024;
#pragma unroll
            for (int sub = 0; sub < 2; sub++)
#pragma unroll
                for (int r = 0; r < 4; r++) {
                    int row = g * 4 + r;
                    *(unsigned short*)(pb + ((row * 64 + (sub * 16 + ln) * 2) ^ SWZ4(row))) =
                        f2bf(S[c][sub][r]);
                }
            bf16x8 pa = *(bf16x8*)(pb + ((ln * 64 + g * 16) ^ SWZ4(ln)));
#pragma unroll
            for (int t4 = 0; t4 < 4; t4++)
                acc[t4] = __builtin_amdgcn_mfma_f32_16x16x32_bf16(
                    pa, vr[c & 1][t4], acc[t4], 0, 0, 0);
        }

        // write partials (max-shifted, unnormalized)
#pragma unroll
        for (int t4 = 0; t4 < 4; t4++)
#pragma unroll
            for (int r = 0; r < 4; r++)
                accP[((long)ks * E_EDGES + bm + g * 4 + r) * 256 + h * 64 + t4 * 16 + ln] =
                    acc[t4][r];
        if (ln == 0) {
#pragma unroll
            for (int r = 0; r < 4; r++) {
                mP[(ks * 4 + h) * E_EDGES + bm + g * 4 + r] = tm[r];
                lP[(ks * 4 + h) * E_EDGES + bm + g * 4 + r] = ps[r];
            }
        }
        return;
    }

    // ================= company GEMM -> ch =================
    {
        const int bm = (bid - 1024) * 64;
        char* abase = lds;
        char* wbase = lds + 4096;
        const int wv = t >> 6;
        const int sr = t >> 2, sc = (t & 3) * 8;

        f32x4 acc[16];
#pragma unroll
        for (int i = 0; i < 16; i++) acc[i] = (f32x4){0.f, 0.f, 0.f, 0.f};

        int arow = bm + sr; if (arow > N_COMP - 1) arow = N_COMP - 1;
        const float* aptr = company_x + (long)arow * 256 + sc;

        for (int kc = 0; kc < 256; kc += 32) {
            __syncthreads();
            stage_f32(aptr + kc, abase, sr, sc);
#pragma unroll
            for (int p = 0; p < 4; p++) {
                int r = p * 64 + sr;
                *(bf16x8*)(wbase + ((r * 64 + sc * 2) ^ SWZ(r))) =
                    *(const bf16x8*)(Wc_bf + (long)r * 256 + kc + sc);
            }
            __syncthreads();
            const int ar = wv * 16 + ln;
            bf16x8 af = *(bf16x8*)(abase + ((ar * 64 + g * 16) ^ SWZ(ar)));
#pragma unroll
            for (int nj = 0; nj < 16; nj++) {
                int wr = nj * 16 + ln;
                bf16x8 bf = *(bf16x8*)(wbase + ((wr * 64 + g * 16) ^ SWZ(wr)));
                acc[nj] = __builtin_amdgcn_mfma_f32_16x16x32_bf16(af, bf, acc[nj], 0, 0, 0);
            }
        }
#pragma unroll
        for (int nj = 0; nj < 16; nj++) {
            int n = nj * 16 + ln;
            float bv = bc[n];
#pragma unroll
            for (int r = 0; r < 4; r++) {
                int m = bm + wv * 16 + g * 4 + r;
                if (m < N_COMP)
                    ch[(long)m * 256 + n] = acc[nj][r] + bv;
            }
        }
    }
}

// ---------------------------------------------------------------------------
// merge_out: exact log-sum-exp merge of the two key-halves, then out-proj
// -> pooled[list[R]]. grid 512 (early-exit vs M), 4 waves, wave = head.
// ---------------------------------------------------------------------------
__global__ __launch_bounds__(256, 2) void merge_out(
    const float* __restrict__ accP, const float* __restrict__ mP,
    const float* __restrict__ lP,
    const unsigned short* __restrict__ wout, const float* __restrict__ b_out,
    const int* __restrict__ list, const int* __restrict__ nlist,
    float* __restrict__ pooled)
{
    const int M = *nlist;
    const int bm = blockIdx.x * 16;
    if (bm >= M) return;

    __shared__ char lds[8192];
    const int t = threadIdx.x, h = t >> 6, lane = t & 63;
    const int g = lane >> 4, ln = lane & 15;
    char* qb = lds + h * 2048;

    float s0[4], s1[4];
    int gr[4];
#pragma unroll
    for (int r = 0; r < 4; r++) {
        int R = bm + g * 4 + r;
        gr[r] = (R > M - 1) ? (M - 1) : R;
        float m0 = mP[(0 + h) * E_EDGES + gr[r]];
        float m1 = mP[(4 + h) * E_EDGES + gr[r]];
        float l0 = lP[(0 + h) * E_EDGES + gr[r]];
        float l1 = lP[(4 + h) * E_EDGES + gr[r]];
        float mn = fmaxf(m0, m1);
        float c0 = __expf(m0 - mn), c1 = __expf(m1 - mn);
        float inv = 1.0f / (l0 * c0 + l1 * c1);
        s0[r] = c0 * inv;
        s1[r] = c1 * inv;
    }
#pragma unroll
    for (int t4 = 0; t4 < 4; t4++)
#pragma unroll
        for (int r = 0; r < 4; r++) {
            int col = h * 64 + t4 * 16 + ln;
            float a0 = accP[((long)0 * E_EDGES + gr[r]) * 256 + col];
            float a1 = accP[((long)1 * E_EDGES + gr[r]) * 256 + col];
            float ctx = a0 * s0[r] + a1 * s1[r];
            int row = g * 4 + r, c2 = t4 * 16 + ln;
            *(unsigned short*)(qb + ((row * 128 + c2 * 2) ^ SWZ(row))) = f2bf(ctx);
        }
    __syncthreads();

    // out-proj cols [64h, 64h+64)
    f32x4 oa[4];
#pragma unroll
    for (int i = 0; i < 4; i++) oa[i] = (f32x4){0.f, 0.f, 0.f, 0.f};
#pragma unroll
    for (int kc = 0; kc < 256; kc += 32) {
        int hs = kc >> 6;
        int off = (kc & 63) + g * 8;
        bf16x8 af = *(bf16x8*)(lds + hs * 2048 + ((ln * 128 + off * 2) ^ SWZ(ln)));
#pragma unroll
        for (int nj = 0; nj < 4; nj++) {
            bf16x8 bf = *(const bf16x8*)(wout + (long)(h * 64 + nj * 16 + ln) * 256 + kc + g * 8);
            oa[nj] = __builtin_amdgcn_mfma_f32_16x16x32_bf16(af, bf, oa[nj], 0, 0, 0);
        }
    }
#pragma unroll
    for (int nj = 0; nj < 4; nj++) {
        int n = h * 64 + nj * 16 + ln;
        float bv = b_out[n];
#pragma unroll
        for (int r = 0; r < 4; r++) {
            int R = bm + g * 4 + r;
            if (R < M)
                pooled[(long)list[R] * 256 + n] = oa[nj][r] + bv;
        }
    }
}

// ---------------------------------------------------------------------------
// fuse_ln: out = LN(ch + factor*pooled) * gamma + beta. Memory-bound,
// wave-per-row, 4 rows/block (round-4 known-good pattern, pooled guarded).
// ---------------------------------------------------------------------------
__global__ __launch_bounds__(256) void fuse_ln(
    const float* __restrict__ ch, const float* __restrict__ pooled,
    const float* __restrict__ csrc, const float* __restrict__ gamma,
    const float* __restrict__ beta, float* __restrict__ out)
{
    const int w = threadIdx.x >> 6, lane = threadIdx.x & 63;
    const int r = blockIdx.x * 4 + w;

    const float4 c = *(const float4*)&ch[(long)r * 256 + lane * 4];
    const float cnt = csrc[r];
    float4 ag = {0.f, 0.f, 0.f, 0.f};
    float factor = 0.f;
    if (cnt > 0.f) {
        ag = *(const float4*)&pooled[(long)r * 256 + lane * 4];
        factor = cnt / (cnt + 1e-6f);
    }

    float o0 = c.x + ag.x * factor;
    float o1 = c.y + ag.y * factor;
    float o2 = c.z + ag.z * factor;
    float o3 = c.w + ag.w * factor;

    float sum = o0 + o1 + o2 + o3;
    float sq  = o0 * o0 + o1 * o1 + o2 * o2 + o3 * o3;
#pragma unroll
    for (int off = 1; off < 64; off <<= 1) {
        sum += __shfl_xor(sum, off);
        sq  += __shfl_xor(sq,  off);
    }
    const float mean = sum * (1.0f / 256.0f);
    const float var  = sq * (1.0f / 256.0f) - mean * mean;
    const float rstd = rsqrtf(var + 1e-5f);

    const float4 gm = *(const float4*)&gamma[lane * 4];
    const float4 bt = *(const float4*)&beta[lane * 4];
    float4 o;
    o.x = (o0 - mean) * rstd * gm.x + bt.x;
    o.y = (o1 - mean) * rstd * gm.y + bt.y;
    o.z = (o2 - mean) * rstd * gm.z + bt.z;
    o.w = (o3 - mean) * rstd * gm.w + bt.w;
    *(float4*)&out[(long)r * 256 + lane * 4] = o;
}

// ---------------------------------------------------------------------------
extern "C" void kernel_launch(void* const* d_in, const int* in_sizes, int n_in,
                              void* d_out, int out_size, void* d_ws, size_t ws_size,
                              hipStream_t stream)
{
    const float* company_x  = (const float*)d_in[0];
    const float* industry_x = (const float*)d_in[1];
    const int*   edge       = (const int*)d_in[2];
    const float* Wc         = (const float*)d_in[3];
    const float* bc         = (const float*)d_in[4];
    const float* Wi         = (const float*)d_in[5];
    const float* bi         = (const float*)d_in[6];
    const float* w_in       = (const float*)d_in[7];
    const float* b_in       = (const float*)d_in[8];
    const float* w_out      = (const float*)d_in[9];
    const float* b_out      = (const float*)d_in[10];
    const float* gamma      = (const float*)d_in[11];
    const float* beta       = (const float*)d_in[12];
    float* out = (float*)d_out;

    const int* src = edge;
    const int* tgt = edge + E_EDGES;

    // workspace carve (float units)
    float* wf = (float*)d_ws;
    size_t o = 0;
    unsigned short* Wc_bf   = (unsigned short*)(wf + o); o += 32768;  // 256x256
    unsigned short* wout_bf = (unsigned short*)(wf + o); o += 32768;
    unsigned short* WcT_bf  = (unsigned short*)(wf + o); o += 32768;
    unsigned short* Wi_bf   = (unsigned short*)(wf + o); o += 16384;  // 256x128
    unsigned short* wkv_bf  = (unsigned short*)(wf + o); o += 65536;  // 512x256
    unsigned short* Wcq_bf  = (unsigned short*)(wf + o); o += 32768;
    unsigned short* Kbuf    = (unsigned short*)(wf + o); o += 65536;  // 512x256
    unsigned short* VTg     = (unsigned short*)(wf + o); o += 65536;  // 256x512
    float* ch               = wf + o; o += (size_t)N_COMP * 256;
    float* pooled           = wf + o; o += (size_t)N_COMP * 256;
    float* accP             = wf + o; o += (size_t)2 * E_EDGES * 256;
    float* mPb              = wf + o; o += (size_t)8 * E_EDGES;
    float* lPb              = wf + o; o += (size_t)8 * E_EDGES;
    float* beff             = wf + o; o += 768;
    float* cntT             = wf + o; o += NKEYS;
    int*   list             = (int*)(wf + o); o += E_EDGES;
    // contiguous zeroed region: csrc | ctgt | nlist
    float* csrc             = wf + o; o += N_COMP;
    float* ctgt             = wf + o; o += NKEYS;
    int*   nlist            = (int*)(wf + o); o += 4;

    hipMemsetAsync(csrc, 0, (N_COMP + NKEYS + 4) * sizeof(float), stream);

    prep<<<dim3(220), dim3(256), 0, stream>>>(
        src, tgt, Wc, Wi, w_out, w_in, bc, bi, b_in,
        csrc, ctgt, Wc_bf, wout_bf, WcT_bf, Wi_bf, wkv_bf, beff);

    fusedW<<<dim3(99), dim3(256), 0, stream>>>(
        w_in, WcT_bf, industry_x, Wi_bf, wkv_bf, beff, ctgt, csrc,
        Wcq_bf, Kbuf, VTg, cntT, list, nlist);

    attn_gemm<<<dim3(1024 + 313), dim3(256), 0, stream>>>(
        company_x, Wcq_bf, beff, Kbuf, VTg, cntT, list, nlist,
        Wc_bf, bc, accP, mPb, lPb, ch);

    merge_out<<<dim3(512), dim3(256), 0, stream>>>(
        accP, mPb, lPb, wout_bf, b_out, list, nlist, pooled);

    fuse_ln<<<dim3(N_COMP / 4), dim3(256), 0, stream>>>(
        ch, pooled, csrc, gamma, beta, out);
}